// Round 1
// baseline (97.549 us; speedup 1.0000x reference)
//
#include <hip/hip_runtime.h>

// Morph2D soft rank-order filter:
//   patches(3x3, zero-pad SAME) * se  -> sort ascending -> dot softmax(rank)
// x: [32,512,512,1] fp32, se: [3,3] fp32, rank: [9] fp32, out: [32,512,512,1] fp32

#define BB 32
#define HH 512
#define WW 512

__global__ void prep_weights(const float* __restrict__ rank, float* __restrict__ w) {
    if (threadIdx.x == 0 && blockIdx.x == 0) {
        float r[9];
        float m = -3.4e38f;
        #pragma unroll
        for (int i = 0; i < 9; ++i) { r[i] = rank[i]; m = fmaxf(m, r[i]); }
        float s = 0.f;
        #pragma unroll
        for (int i = 0; i < 9; ++i) { r[i] = expf(r[i] - m); s += r[i]; }
        float inv = 1.0f / s;
        #pragma unroll
        for (int i = 0; i < 9; ++i) w[i] = r[i] * inv;
    }
}

#define CSWAP(a,b) { float lo_ = fminf(v[a], v[b]); float hi_ = fmaxf(v[a], v[b]); v[a] = lo_; v[b] = hi_; }

__global__ __launch_bounds__(256) void morph2d_kernel(
    const float* __restrict__ x, const float* __restrict__ se9,
    const float* __restrict__ w9, float* __restrict__ out)
{
    // one thread = 4 consecutive pixels along W (aligned float4 in/out)
    int g  = blockIdx.x * blockDim.x + threadIdx.x;   // 2,097,152 total, exact
    int gx = g & 127;            // W/4 = 128 groups per row
    int y  = (g >> 7) & 511;
    int b  = g >> 16;            // 128*512 = 65536 groups per batch image
    int x4 = gx << 2;

    // uniform loads -> expect s_load scalarization
    float se[9], w[9];
    #pragma unroll
    for (int i = 0; i < 9; ++i) { se[i] = se9[i]; w[i] = w9[i]; }

    // 3 rows x 6 columns: [x4-1 .. x4+4], zero-padded at borders
    float rowv[3][6];
    #pragma unroll
    for (int dy = 0; dy < 3; ++dy) {
        int ry = y + dy - 1;
        if (ry < 0 || ry >= HH) {
            #pragma unroll
            for (int i = 0; i < 6; ++i) rowv[dy][i] = 0.f;
        } else {
            const float* r = x + ((size_t)b * HH + ry) * WW;
            float4 c = *(const float4*)(r + x4);
            rowv[dy][1] = c.x; rowv[dy][2] = c.y; rowv[dy][3] = c.z; rowv[dy][4] = c.w;
            rowv[dy][0] = (x4 == 0)        ? 0.f : r[x4 - 1];
            rowv[dy][5] = (x4 + 4 >= WW)   ? 0.f : r[x4 + 4];
        }
    }

    float4 res;
    float* resp = &res.x;
    #pragma unroll
    for (int j = 0; j < 4; ++j) {
        float v[9];
        #pragma unroll
        for (int dy = 0; dy < 3; ++dy) {
            v[dy*3+0] = rowv[dy][j]   * se[dy*3+0];
            v[dy*3+1] = rowv[dy][j+1] * se[dy*3+1];
            v[dy*3+2] = rowv[dy][j+2] * se[dy*3+2];
        }
        // optimal 9-input sorting network: 25 CE, depth 7 (Dobbelaere)
        CSWAP(0,3) CSWAP(1,7) CSWAP(2,5) CSWAP(4,8)
        CSWAP(0,7) CSWAP(2,4) CSWAP(3,8) CSWAP(5,6)
        CSWAP(0,2) CSWAP(1,3) CSWAP(4,5) CSWAP(7,8)
        CSWAP(1,4) CSWAP(3,6) CSWAP(5,7)
        CSWAP(0,1) CSWAP(2,4) CSWAP(3,5) CSWAP(6,8)
        CSWAP(2,3) CSWAP(4,5) CSWAP(6,7)
        CSWAP(1,2) CSWAP(3,4) CSWAP(5,6)

        float acc = 0.f;
        #pragma unroll
        for (int i = 0; i < 9; ++i) acc = fmaf(v[i], w[i], acc);
        resp[j] = acc;
    }

    *(float4*)(out + (((size_t)b * HH + y) * WW + x4)) = res;
}

extern "C" void kernel_launch(void* const* d_in, const int* in_sizes, int n_in,
                              void* d_out, int out_size, void* d_ws, size_t ws_size,
                              hipStream_t stream) {
    const float* x    = (const float*)d_in[0];
    const float* se   = (const float*)d_in[1];
    const float* rank = (const float*)d_in[2];
    float* w9  = (float*)d_ws;
    float* out = (float*)d_out;

    prep_weights<<<1, 64, 0, stream>>>(rank, w9);

    const int total_groups = BB * HH * (WW / 4);       // 2,097,152
    morph2d_kernel<<<total_groups / 256, 256, 0, stream>>>(x, se, w9, out);
}